// Round 1
// baseline (651.234 us; speedup 1.0000x reference)
//
#include <hip/hip_runtime.h>
#include <hip/hip_bf16.h>

// Problem constants (fixed by the reference)
#define N_NODES 100000
#define N_EDGES 1600000
#define F_NODE 128
#define F_EDGE 128
#define HIDDEN 256
#define OUT_F 128
#define K_DIM 256  // fan_in1 == HIDDEN == 256

using f32x4 = __attribute__((ext_vector_type(4))) float;
using s16x8 = __attribute__((ext_vector_type(8))) short;

static __device__ __forceinline__ short f2b(float f) {
  // f32 -> bf16 round-to-nearest-even (inputs are finite normals, no NaN path)
  union { float f; unsigned u; } v; v.f = f;
  unsigned r = v.u + 0x7fffu + ((v.u >> 16) & 1u);
  return (short)(r >> 16);
}

// ---------------- Phase 1: bucket edges by destination node ----------------

__global__ void k_count(const int* __restrict__ col, unsigned* __restrict__ counts) {
  int e = blockIdx.x * blockDim.x + threadIdx.x;
  if (e < N_EDGES) atomicAdd(&counts[col[e]], 1u);
}

__global__ void k_offsets(const unsigned* __restrict__ counts,
                          unsigned* __restrict__ offsets,
                          unsigned* __restrict__ cursor,
                          unsigned* __restrict__ total) {
  int n = blockIdx.x * blockDim.x + threadIdx.x;
  if (n < N_NODES) {
    unsigned c = counts[n];
    unsigned o = atomicAdd(total, c);   // order-free partition; any unique ranges work
    offsets[n] = o;
    cursor[n] = o;
  }
}

__global__ void k_fill(const int* __restrict__ col,
                       unsigned* __restrict__ cursor,
                       unsigned* __restrict__ edge_ids) {
  int e = blockIdx.x * blockDim.x + threadIdx.x;
  if (e < N_EDGES) {
    unsigned slot = atomicAdd(&cursor[col[e]], 1u);
    edge_ids[slot] = (unsigned)e;
  }
}

// -------- Phase 2: gather-sum per node, mean, build Hin = [x | agg] bf16 ----

__global__ void k_agg(const float* __restrict__ x,
                      const float* __restrict__ edge_attr,
                      const unsigned* __restrict__ offsets,
                      const unsigned* __restrict__ counts,
                      const unsigned* __restrict__ edge_ids,
                      short* __restrict__ hin) {
  // one wave (64 lanes) per node; each lane owns 2 features via float2
  int n = (int)((blockIdx.x * (unsigned)blockDim.x + threadIdx.x) >> 6);
  int lane = threadIdx.x & 63;
  if (n >= N_NODES) return;
  unsigned off = offsets[n], cnt = counts[n];
  float a0 = 0.f, a1 = 0.f;
  const float* ea = edge_attr + 2 * lane;
  for (unsigned i = 0; i < cnt; ++i) {
    unsigned e = edge_ids[off + i];
    float2 v = *reinterpret_cast<const float2*>(ea + (size_t)e * F_EDGE);
    a0 += v.x; a1 += v.y;
  }
  float inv = 1.0f / (float)(cnt > 0u ? cnt : 1u);
  float2 xv = *reinterpret_cast<const float2*>(x + (size_t)n * F_NODE + 2 * lane);
  short2 hx; hx.x = f2b(xv.x);     hx.y = f2b(xv.y);
  short2 hm; hm.x = f2b(a0 * inv); hm.y = f2b(a1 * inv);
  short* hrow = hin + (size_t)n * K_DIM;
  *reinterpret_cast<short2*>(hrow + 2 * lane) = hx;
  *reinterpret_cast<short2*>(hrow + F_NODE + 2 * lane) = hm;
}

// ---------------- Phase 3: weights f32 -> bf16 ----------------

__global__ void k_cvt(const float* __restrict__ w, short* __restrict__ wb, int n) {
  int i = blockIdx.x * blockDim.x + threadIdx.x;
  if (i < n) wb[i] = f2b(w[i]);
}

// ---------------- Phase 4: bf16 MFMA GEMM, C = relu?(A @ B^T + bias) --------
// A: [M x 256] bf16 row-major. B: [NCOLS x 256] bf16 (row = output col, K contig).
// Block tile 128x128, 4 waves in 2x2, wave tile 64x64 (4x4 fragments of 16x16x32).

template<int NCOLS, bool RELU, bool OUT_BF16>
__global__ __launch_bounds__(256) void k_gemm(const short* __restrict__ A,
                                              const short* __restrict__ B,
                                              const float* __restrict__ bias,
                                              void* __restrict__ Cv, int M) {
  const int lane = threadIdx.x & 63;
  const int wid  = threadIdx.x >> 6;
  const int wr = wid >> 1, wc = wid & 1;
  const int rowbase = blockIdx.x * 128 + wr * 64;
  const int colbase = blockIdx.y * 128 + wc * 64;
  const int lr = lane & 15;         // row (A) / col (B) within fragment
  const int lk = (lane >> 4) * 8;   // k offset within fragment (8 contig bf16)

  f32x4 acc[4][4] = {};
  for (int ks = 0; ks < K_DIM; ks += 32) {
    s16x8 a[4], b[4];
#pragma unroll
    for (int m = 0; m < 4; ++m) {
      int r = rowbase + m * 16 + lr;
      r = r < M ? r : M - 1;  // clamp pad rows to a valid address
      a[m] = *reinterpret_cast<const s16x8*>(A + (size_t)r * K_DIM + ks + lk);
    }
#pragma unroll
    for (int nn = 0; nn < 4; ++nn) {
      int c = colbase + nn * 16 + lr;
      b[nn] = *reinterpret_cast<const s16x8*>(B + (size_t)c * K_DIM + ks + lk);
    }
#pragma unroll
    for (int m = 0; m < 4; ++m)
#pragma unroll
      for (int nn = 0; nn < 4; ++nn)
        acc[m][nn] = __builtin_amdgcn_mfma_f32_16x16x32_bf16(a[m], b[nn], acc[m][nn], 0, 0, 0);
  }
  // epilogue: C/D layout col = lane&15, row = (lane>>4)*4 + j  [m89/m91 verified]
#pragma unroll
  for (int m = 0; m < 4; ++m) {
#pragma unroll
    for (int nn = 0; nn < 4; ++nn) {
      int c = colbase + nn * 16 + lr;
      float bv = bias[c];
#pragma unroll
      for (int j = 0; j < 4; ++j) {
        int r = rowbase + m * 16 + (lane >> 4) * 4 + j;
        if (r < M) {
          float v = acc[m][nn][j] + bv;
          if (RELU) v = v > 0.f ? v : 0.f;
          if (OUT_BF16) ((short*)Cv)[(size_t)r * NCOLS + c] = f2b(v);
          else          ((float*)Cv)[(size_t)r * NCOLS + c] = v;
        }
      }
    }
  }
}

// ---------------- launch ----------------

extern "C" void kernel_launch(void* const* d_in, const int* in_sizes, int n_in,
                              void* d_out, int out_size, void* d_ws, size_t ws_size,
                              hipStream_t stream) {
  const float* x         = (const float*)d_in[0];
  const int*   edge_idx  = (const int*)d_in[1];      // [2 x N_EDGES], int32
  const int*   col       = edge_idx + N_EDGES;       // row 1 = destinations
  const float* edge_attr = (const float*)d_in[2];
  const float* W1        = (const float*)d_in[3];
  const float* b1        = (const float*)d_in[4];
  const float* W2        = (const float*)d_in[5];
  const float* b2        = (const float*)d_in[6];
  float* out = (float*)d_out;

  // workspace layout (bytes), all 16B-aligned
  char* ws = (char*)d_ws;
  unsigned* counts   = (unsigned*)(ws + 0);              // 400,000
  unsigned* total    = (unsigned*)(ws + 400000);         // 4 (+12 pad)
  unsigned* offsets  = (unsigned*)(ws + 400016);         // 400,000
  unsigned* cursor   = (unsigned*)(ws + 800016);         // 400,000
  unsigned* edge_ids = (unsigned*)(ws + 1200016);        // 6,400,000
  short*    hin      = (short*)   (ws + 7600016);        // 51,200,000 (bf16 bits)
  short*    h1       = (short*)   (ws + 58800016);       // 51,200,000
  short*    w1b      = (short*)   (ws + 110000016);      // 131,072
  short*    w2b      = (short*)   (ws + 110131088);      // 65,536
  // total ~110.2 MB

  // zero counts + total (everything else is fully overwritten each call)
  hipMemsetAsync(ws, 0, 400004, stream);

  k_count  <<<(N_EDGES + 255) / 256, 256, 0, stream>>>(col, counts);
  k_offsets<<<(N_NODES + 255) / 256, 256, 0, stream>>>(counts, offsets, cursor, total);
  k_fill   <<<(N_EDGES + 255) / 256, 256, 0, stream>>>(col, cursor, edge_ids);
  k_agg    <<<N_NODES / 4, 256, 0, stream>>>(x, edge_attr, offsets, counts, edge_ids, hin);

  k_cvt<<<(HIDDEN * K_DIM + 255) / 256, 256, 0, stream>>>(W1, w1b, HIDDEN * K_DIM);
  k_cvt<<<(OUT_F  * HIDDEN + 255) / 256, 256, 0, stream>>>(W2, w2b, OUT_F * HIDDEN);

  dim3 g1((N_NODES + 127) / 128, HIDDEN / 128);
  k_gemm<HIDDEN, true,  true ><<<g1, 256, 0, stream>>>(hin, w1b, b1, h1, N_NODES);
  dim3 g2((N_NODES + 127) / 128, OUT_F / 128);
  k_gemm<OUT_F,  false, false><<<g2, 256, 0, stream>>>(h1, w2b, b2, out, N_NODES);
}

// Round 2
// 554.582 us; speedup vs baseline: 1.1743x; 1.1743x over previous
//
#include <hip/hip_runtime.h>
#include <hip/hip_bf16.h>

// Problem constants (fixed by the reference)
#define N_NODES 100000
#define N_EDGES 1600000
#define F_NODE 128
#define F_EDGE 128
#define HIDDEN 256
#define OUT_F 128
#define K_DIM 256  // fan_in1 == HIDDEN == 256

using f32x4 = __attribute__((ext_vector_type(4))) float;
using s16x8 = __attribute__((ext_vector_type(8))) short;

static __device__ __forceinline__ short f2b(float f) {
  // f32 -> bf16 round-to-nearest-even (inputs are finite normals, no NaN path)
  union { float f; unsigned u; } v; v.f = f;
  unsigned r = v.u + 0x7fffu + ((v.u >> 16) & 1u);
  return (short)(r >> 16);
}

// ---------------- Phase 1: bucket edges by destination node ----------------

__global__ void k_count(const int* __restrict__ col, unsigned* __restrict__ counts) {
  int e = blockIdx.x * blockDim.x + threadIdx.x;
  if (e < N_EDGES) atomicAdd(&counts[col[e]], 1u);
}

// Exclusive-offset assignment: wave-scan counts, ONE atomic per wave (not per
// thread!) on the shared cursor. 100k same-address atomics -> 1563.
__global__ void k_offsets(const unsigned* __restrict__ counts,
                          unsigned* __restrict__ offsets,
                          unsigned* __restrict__ cursor,
                          unsigned* __restrict__ total) {
  int n = blockIdx.x * blockDim.x + threadIdx.x;
  int lane = threadIdx.x & 63;
  unsigned c = (n < N_NODES) ? counts[n] : 0u;
  // inclusive scan across the wave
  unsigned s = c;
#pragma unroll
  for (int d = 1; d < 64; d <<= 1) {
    unsigned t = __shfl_up(s, d, 64);
    if (lane >= d) s += t;
  }
  unsigned wave_sum = __shfl(s, 63, 64);
  unsigned base = 0;
  if (lane == 63) base = atomicAdd(total, wave_sum);  // order-free partition
  base = __shfl(base, 63, 64);
  if (n < N_NODES) {
    unsigned o = base + s - c;  // exclusive offset
    offsets[n] = o;
    cursor[n] = o;
  }
}

__global__ void k_fill(const int* __restrict__ col,
                       unsigned* __restrict__ cursor,
                       unsigned* __restrict__ edge_ids) {
  int e = blockIdx.x * blockDim.x + threadIdx.x;
  if (e < N_EDGES) {
    unsigned slot = atomicAdd(&cursor[col[e]], 1u);
    edge_ids[slot] = (unsigned)e;
  }
}

// -------- Phase 2: gather-sum per node, mean, build Hin = [x | agg] bf16 ----

__global__ void k_agg(const float* __restrict__ x,
                      const float* __restrict__ edge_attr,
                      const unsigned* __restrict__ offsets,
                      const unsigned* __restrict__ counts,
                      const unsigned* __restrict__ edge_ids,
                      short* __restrict__ hin) {
  // one wave (64 lanes) per node; each lane owns 2 features via float2
  int n = (int)((blockIdx.x * (unsigned)blockDim.x + threadIdx.x) >> 6);
  int lane = threadIdx.x & 63;
  if (n >= N_NODES) return;
  unsigned off = offsets[n], cnt = counts[n];
  float a0 = 0.f, a1 = 0.f;
  const float* ea = edge_attr + 2 * lane;
  unsigned i = 0;
  // unroll x4: 4 independent 512B row gathers in flight per wave
  for (; i + 4 <= cnt; i += 4) {
    unsigned e0 = edge_ids[off + i + 0];
    unsigned e1 = edge_ids[off + i + 1];
    unsigned e2 = edge_ids[off + i + 2];
    unsigned e3 = edge_ids[off + i + 3];
    float2 v0 = *reinterpret_cast<const float2*>(ea + (size_t)e0 * F_EDGE);
    float2 v1 = *reinterpret_cast<const float2*>(ea + (size_t)e1 * F_EDGE);
    float2 v2 = *reinterpret_cast<const float2*>(ea + (size_t)e2 * F_EDGE);
    float2 v3 = *reinterpret_cast<const float2*>(ea + (size_t)e3 * F_EDGE);
    a0 += v0.x + v1.x + v2.x + v3.x;
    a1 += v0.y + v1.y + v2.y + v3.y;
  }
  for (; i < cnt; ++i) {
    unsigned e = edge_ids[off + i];
    float2 v = *reinterpret_cast<const float2*>(ea + (size_t)e * F_EDGE);
    a0 += v.x; a1 += v.y;
  }
  float inv = 1.0f / (float)(cnt > 0u ? cnt : 1u);
  float2 xv = *reinterpret_cast<const float2*>(x + (size_t)n * F_NODE + 2 * lane);
  short2 hx; hx.x = f2b(xv.x);     hx.y = f2b(xv.y);
  short2 hm; hm.x = f2b(a0 * inv); hm.y = f2b(a1 * inv);
  short* hrow = hin + (size_t)n * K_DIM;
  *reinterpret_cast<short2*>(hrow + 2 * lane) = hx;
  *reinterpret_cast<short2*>(hrow + F_NODE + 2 * lane) = hm;
}

// ---------------- Phase 3: weights f32 -> bf16 ----------------

__global__ void k_cvt(const float* __restrict__ w, short* __restrict__ wb, int n) {
  int i = blockIdx.x * blockDim.x + threadIdx.x;
  if (i < n) wb[i] = f2b(w[i]);
}

// ---------------- Phase 4: bf16 MFMA GEMM, C = relu?(A @ B^T + bias) --------
// A: [M x 256] bf16 row-major. B: [NCOLS x 256] bf16 (row = output col, K contig).
// Block tile 128x128, 4 waves in 2x2, wave tile 64x64 (4x4 fragments of 16x16x32).

template<int NCOLS, bool RELU, bool OUT_BF16>
__global__ __launch_bounds__(256) void k_gemm(const short* __restrict__ A,
                                              const short* __restrict__ B,
                                              const float* __restrict__ bias,
                                              void* __restrict__ Cv, int M) {
  const int lane = threadIdx.x & 63;
  const int wid  = threadIdx.x >> 6;
  const int wr = wid >> 1, wc = wid & 1;
  const int rowbase = blockIdx.x * 128 + wr * 64;
  const int colbase = blockIdx.y * 128 + wc * 64;
  const int lr = lane & 15;         // row (A) / col (B) within fragment
  const int lk = (lane >> 4) * 8;   // k offset within fragment (8 contig bf16)

  f32x4 acc[4][4] = {};
  for (int ks = 0; ks < K_DIM; ks += 32) {
    s16x8 a[4], b[4];
#pragma unroll
    for (int m = 0; m < 4; ++m) {
      int r = rowbase + m * 16 + lr;
      r = r < M ? r : M - 1;  // clamp pad rows to a valid address
      a[m] = *reinterpret_cast<const s16x8*>(A + (size_t)r * K_DIM + ks + lk);
    }
#pragma unroll
    for (int nn = 0; nn < 4; ++nn) {
      int c = colbase + nn * 16 + lr;
      b[nn] = *reinterpret_cast<const s16x8*>(B + (size_t)c * K_DIM + ks + lk);
    }
#pragma unroll
    for (int m = 0; m < 4; ++m)
#pragma unroll
      for (int nn = 0; nn < 4; ++nn)
        acc[m][nn] = __builtin_amdgcn_mfma_f32_16x16x32_bf16(a[m], b[nn], acc[m][nn], 0, 0, 0);
  }
  // epilogue: C/D layout col = lane&15, row = (lane>>4)*4 + j  [m89/m91 verified]
#pragma unroll
  for (int m = 0; m < 4; ++m) {
#pragma unroll
    for (int nn = 0; nn < 4; ++nn) {
      int c = colbase + nn * 16 + lr;
      float bv = bias[c];
#pragma unroll
      for (int j = 0; j < 4; ++j) {
        int r = rowbase + m * 16 + (lane >> 4) * 4 + j;
        if (r < M) {
          float v = acc[m][nn][j] + bv;
          if (RELU) v = v > 0.f ? v : 0.f;
          if (OUT_BF16) ((short*)Cv)[(size_t)r * NCOLS + c] = f2b(v);
          else          ((float*)Cv)[(size_t)r * NCOLS + c] = v;
        }
      }
    }
  }
}

// ---------------- launch ----------------

extern "C" void kernel_launch(void* const* d_in, const int* in_sizes, int n_in,
                              void* d_out, int out_size, void* d_ws, size_t ws_size,
                              hipStream_t stream) {
  const float* x         = (const float*)d_in[0];
  const int*   edge_idx  = (const int*)d_in[1];      // [2 x N_EDGES], int32
  const int*   col       = edge_idx + N_EDGES;       // row 1 = destinations
  const float* edge_attr = (const float*)d_in[2];
  const float* W1        = (const float*)d_in[3];
  const float* b1        = (const float*)d_in[4];
  const float* W2        = (const float*)d_in[5];
  const float* b2        = (const float*)d_in[6];
  float* out = (float*)d_out;

  // workspace layout (bytes), all 16B-aligned
  char* ws = (char*)d_ws;
  unsigned* counts   = (unsigned*)(ws + 0);              // 400,000
  unsigned* total    = (unsigned*)(ws + 400000);         // 4 (+12 pad)
  unsigned* offsets  = (unsigned*)(ws + 400016);         // 400,000
  unsigned* cursor   = (unsigned*)(ws + 800016);         // 400,000
  unsigned* edge_ids = (unsigned*)(ws + 1200016);        // 6,400,000
  short*    hin      = (short*)   (ws + 7600016);        // 51,200,000 (bf16 bits)
  short*    h1       = (short*)   (ws + 58800016);       // 51,200,000
  short*    w1b      = (short*)   (ws + 110000016);      // 131,072
  short*    w2b      = (short*)   (ws + 110131088);      // 65,536
  // total ~110.2 MB

  // zero counts + total (everything else is fully overwritten each call)
  hipMemsetAsync(ws, 0, 400004, stream);

  k_count  <<<(N_EDGES + 255) / 256, 256, 0, stream>>>(col, counts);
  k_offsets<<<(N_NODES + 255) / 256, 256, 0, stream>>>(counts, offsets, cursor, total);
  k_fill   <<<(N_EDGES + 255) / 256, 256, 0, stream>>>(col, cursor, edge_ids);
  k_agg    <<<N_NODES / 4, 256, 0, stream>>>(x, edge_attr, offsets, counts, edge_ids, hin);

  k_cvt<<<(HIDDEN * K_DIM + 255) / 256, 256, 0, stream>>>(W1, w1b, HIDDEN * K_DIM);
  k_cvt<<<(OUT_F  * HIDDEN + 255) / 256, 256, 0, stream>>>(W2, w2b, OUT_F * HIDDEN);

  dim3 g1((N_NODES + 127) / 128, HIDDEN / 128);
  k_gemm<HIDDEN, true,  true ><<<g1, 256, 0, stream>>>(hin, w1b, b1, h1, N_NODES);
  dim3 g2((N_NODES + 127) / 128, OUT_F / 128);
  k_gemm<OUT_F,  false, false><<<g2, 256, 0, stream>>>(h1, w2b, b2, out, N_NODES);
}

// Round 3
// 521.072 us; speedup vs baseline: 1.2498x; 1.0643x over previous
//
#include <hip/hip_runtime.h>
#include <hip/hip_bf16.h>
#include <stdint.h>

// Problem constants (fixed by the reference)
#define N_NODES 100000
#define N_EDGES 1600000
#define F_NODE 128
#define F_EDGE 128
#define HIDDEN 256
#define OUT_F 128
#define K_DIM 256  // fan_in1 == HIDDEN == 256

using f32x4 = __attribute__((ext_vector_type(4))) float;
using s16x8 = __attribute__((ext_vector_type(8))) short;

typedef __attribute__((address_space(3))) unsigned lds_u32;
typedef __attribute__((address_space(1))) const unsigned gbl_u32;

static __device__ __forceinline__ short f2b(float f) {
  // f32 -> bf16 round-to-nearest-even (finite inputs)
  union { float f; unsigned u; } v; v.f = f;
  unsigned r = v.u + 0x7fffu + ((v.u >> 16) & 1u);
  return (short)(r >> 16);
}

static __device__ __forceinline__ void gld_lds16(const void* g, void* l) {
  __builtin_amdgcn_global_load_lds((gbl_u32*)g, (lds_u32*)l, 16, 0, 0);
}

// ---------------- Phase 1: bucket edges by destination node ----------------

__global__ void k_count(const int* __restrict__ col, unsigned* __restrict__ counts) {
  int e = blockIdx.x * blockDim.x + threadIdx.x;
  if (e < N_EDGES) atomicAdd(&counts[col[e]], 1u);
}

// wave-scan counts, ONE same-address atomic per wave (not per thread)
__global__ void k_offsets(const unsigned* __restrict__ counts,
                          unsigned* __restrict__ offsets,
                          unsigned* __restrict__ cursor,
                          unsigned* __restrict__ total) {
  int n = blockIdx.x * blockDim.x + threadIdx.x;
  int lane = threadIdx.x & 63;
  unsigned c = (n < N_NODES) ? counts[n] : 0u;
  unsigned s = c;
#pragma unroll
  for (int d = 1; d < 64; d <<= 1) {
    unsigned t = __shfl_up(s, d, 64);
    if (lane >= d) s += t;
  }
  unsigned wave_sum = __shfl(s, 63, 64);
  unsigned base = 0;
  if (lane == 63) base = atomicAdd(total, wave_sum);  // order-free partition
  base = __shfl(base, 63, 64);
  if (n < N_NODES) {
    unsigned o = base + s - c;
    offsets[n] = o;
    cursor[n] = o;
  }
}

__global__ void k_fill(const int* __restrict__ col,
                       unsigned* __restrict__ cursor,
                       unsigned* __restrict__ edge_ids) {
  int e = blockIdx.x * blockDim.x + threadIdx.x;
  if (e < N_EDGES) {
    unsigned slot = atomicAdd(&cursor[col[e]], 1u);
    edge_ids[slot] = (unsigned)e;
  }
}

// -------- Phase 2: gather-sum per node, mean, build Hin = [x | agg] bf16 ----
// one wave per node; 32 lanes x float4 = one 512B edge row; both wave halves
// process different edges -> 2 edges/iter, unroll x4 -> 8 rows in flight.

__global__ void k_agg(const float* __restrict__ x,
                      const float* __restrict__ edge_attr,
                      const unsigned* __restrict__ offsets,
                      const unsigned* __restrict__ counts,
                      const unsigned* __restrict__ edge_ids,
                      short* __restrict__ hin) {
  int n = (int)((blockIdx.x * (unsigned)blockDim.x + threadIdx.x) >> 6);
  int lane = threadIdx.x & 63;
  if (n >= N_NODES) return;
  int half = lane >> 5, l32 = lane & 31;
  unsigned off = offsets[n], cnt = counts[n];
  f32x4 a = {0.f, 0.f, 0.f, 0.f};
  const float* eb = edge_attr + 4 * l32;
  unsigned i = 0;
  for (; i + 8 <= cnt; i += 8) {
    unsigned e0 = edge_ids[off + i + 0 + half];
    unsigned e1 = edge_ids[off + i + 2 + half];
    unsigned e2 = edge_ids[off + i + 4 + half];
    unsigned e3 = edge_ids[off + i + 6 + half];
    f32x4 v0 = *reinterpret_cast<const f32x4*>(eb + (size_t)e0 * F_EDGE);
    f32x4 v1 = *reinterpret_cast<const f32x4*>(eb + (size_t)e1 * F_EDGE);
    f32x4 v2 = *reinterpret_cast<const f32x4*>(eb + (size_t)e2 * F_EDGE);
    f32x4 v3 = *reinterpret_cast<const f32x4*>(eb + (size_t)e3 * F_EDGE);
    a += v0 + v1 + v2 + v3;
  }
  for (; i + 2 <= cnt; i += 2) {
    unsigned e = edge_ids[off + i + half];
    a += *reinterpret_cast<const f32x4*>(eb + (size_t)e * F_EDGE);
  }
  if (i < cnt && half == 0) {
    unsigned e = edge_ids[off + i];
    a += *reinterpret_cast<const f32x4*>(eb + (size_t)e * F_EDGE);
  }
  // combine the two halves (both end up with the full sum)
  f32x4 b;
  b[0] = __shfl_xor(a[0], 32); b[1] = __shfl_xor(a[1], 32);
  b[2] = __shfl_xor(a[2], 32); b[3] = __shfl_xor(a[3], 32);
  a += b;
  float inv = 1.0f / (float)(cnt > 0u ? cnt : 1u);
  // x part: 64 lanes x float2
  float2 xv = *reinterpret_cast<const float2*>(x + (size_t)n * F_NODE + 2 * lane);
  short2 hx; hx.x = f2b(xv.x); hx.y = f2b(xv.y);
  short* hrow = hin + (size_t)n * K_DIM;
  *reinterpret_cast<short2*>(hrow + 2 * lane) = hx;
  // agg part: lanes 0..31 write 4 features each
  if (half == 0) {
    short4 hm;
    hm.x = f2b(a[0] * inv); hm.y = f2b(a[1] * inv);
    hm.z = f2b(a[2] * inv); hm.w = f2b(a[3] * inv);
    *reinterpret_cast<short4*>(hrow + F_NODE + 4 * l32) = hm;
  }
}

// ---------------- Phase 3: weights f32 -> bf16 (both in one kernel) --------

__global__ void k_cvt2(const float* __restrict__ W1, const float* __restrict__ W2,
                       short* __restrict__ w1b, short* __restrict__ w2b) {
  int i = (blockIdx.x * blockDim.x + threadIdx.x) * 4;  // 4 elems/thread
  if (i < HIDDEN * K_DIM) {
    f32x4 v = *reinterpret_cast<const f32x4*>(W1 + i);
    short4 s; s.x = f2b(v[0]); s.y = f2b(v[1]); s.z = f2b(v[2]); s.w = f2b(v[3]);
    *reinterpret_cast<short4*>(w1b + i) = s;
  } else {
    int j = i - HIDDEN * K_DIM;
    if (j < OUT_F * HIDDEN) {
      f32x4 v = *reinterpret_cast<const f32x4*>(W2 + j);
      short4 s; s.x = f2b(v[0]); s.y = f2b(v[1]); s.z = f2b(v[2]); s.w = f2b(v[3]);
      *reinterpret_cast<short4*>(w2b + j) = s;
    }
  }
}

// ------------- Phase 4: fused MLP  out = relu(Hin@W1^T+b1)@W2^T + b2 -------
// Block: 128 rows, 512 threads (8 waves). Whole K=256 staged in LDS (64 KB),
// H1 (128x256 bf16) written back into the SAME LDS buffer; never hits HBM.
// LDS layout [row][512B], byte-swizzled: kb' = kb ^ ((row&15)<<5)  -> 2-way
// max bank aliasing on ds_read_b128 fragments (free, m136).

__global__ __launch_bounds__(512) void k_mlp(const short* __restrict__ A,
                                             const short* __restrict__ W1b,
                                             const float* __restrict__ b1,
                                             const short* __restrict__ W2b,
                                             const float* __restrict__ b2,
                                             float* __restrict__ out, int M) {
  __shared__ short lds[128 * 256];  // 64 KB
  const int t = threadIdx.x;
  const int lane = t & 63, wid = t >> 6;
  const int mrow0 = blockIdx.x * 128;
  const int lr = lane & 15;
  const int lkb = (lane >> 4) << 4;  // k byte offset within fragment: 0/16/32/48

  // ---- stage A tile: 128 rows x 512B, pre-swizzled global source ----
  char* ldsb = (char*)lds;
#pragma unroll
  for (int j = 0; j < 8; ++j) {
    int chunk = j * 512 + t;               // 16B chunk index
    int row = chunk >> 5;
    int kb = (chunk & 31) << 4;
    int src_kb = kb ^ ((row & 15) << 5);
    int grow = mrow0 + row; grow = grow < M ? grow : M - 1;
    const char* gsrc = (const char*)A + (size_t)grow * 512 + src_kb;
    // wave-uniform LDS base; HW adds lane*16
    char* ldst = ldsb + (size_t)(j * 512 + wid * 64) * 16;
    gld_lds16(gsrc, ldst);
  }
  __syncthreads();

  // ---- GEMM1: H1[128x256] = relu(A @ W1^T + b1) ----
  const int wr = wid >> 2;   // 0..1: 64-row half
  const int wc = wid & 3;    // 0..3: 64-col quarter
  f32x4 acc1[4][4] = {};
  for (int ksb = 0; ksb < 512; ksb += 64) {  // 32 bf16 per step
    s16x8 af[4], bf[4];
#pragma unroll
    for (int m = 0; m < 4; ++m) {
      int row = wr * 64 + m * 16 + lr;
      int kb = (ksb + lkb) ^ ((row & 15) << 5);
      af[m] = *reinterpret_cast<const s16x8*>(ldsb + row * 512 + kb);
    }
#pragma unroll
    for (int nn = 0; nn < 4; ++nn) {
      int c = wc * 64 + nn * 16 + lr;
      bf[nn] = *reinterpret_cast<const s16x8*>(W1b + (size_t)c * 256 + ((ksb + lkb) >> 1));
    }
#pragma unroll
    for (int m = 0; m < 4; ++m)
#pragma unroll
      for (int nn = 0; nn < 4; ++nn)
        acc1[m][nn] = __builtin_amdgcn_mfma_f32_16x16x32_bf16(af[m], bf[nn], acc1[m][nn], 0, 0, 0);
  }
  __syncthreads();  // all waves done reading A before overwriting LDS with H1

  // epilogue 1: bias+relu -> bf16 into LDS (same swizzle scheme)
#pragma unroll
  for (int nn = 0; nn < 4; ++nn) {
    int c = wc * 64 + nn * 16 + lr;
    float bv = b1[c];
#pragma unroll
    for (int m = 0; m < 4; ++m) {
#pragma unroll
      for (int j = 0; j < 4; ++j) {
        int r = wr * 64 + m * 16 + (lane >> 4) * 4 + j;
        float v = acc1[m][nn][j] + bv;
        v = v > 0.f ? v : 0.f;
        *reinterpret_cast<short*>(ldsb + r * 512 + ((c * 2) ^ ((r & 15) << 5))) = f2b(v);
      }
    }
  }
  __syncthreads();

  // ---- GEMM2: out[128x128] = H1 @ W2^T + b2 ----
  const int wr2 = wid >> 1;  // 0..3: 32-row strip
  const int wc2 = wid & 1;   // 0..1: 64-col half
  f32x4 acc2[2][4] = {};
  for (int ksb = 0; ksb < 512; ksb += 64) {
    s16x8 af[2], bf[4];
#pragma unroll
    for (int m = 0; m < 2; ++m) {
      int row = wr2 * 32 + m * 16 + lr;
      int kb = (ksb + lkb) ^ ((row & 15) << 5);
      af[m] = *reinterpret_cast<const s16x8*>(ldsb + row * 512 + kb);
    }
#pragma unroll
    for (int nn = 0; nn < 4; ++nn) {
      int c = wc2 * 64 + nn * 16 + lr;
      bf[nn] = *reinterpret_cast<const s16x8*>(W2b + (size_t)c * 256 + ((ksb + lkb) >> 1));
    }
#pragma unroll
    for (int m = 0; m < 2; ++m)
#pragma unroll
      for (int nn = 0; nn < 4; ++nn)
        acc2[m][nn] = __builtin_amdgcn_mfma_f32_16x16x32_bf16(af[m], bf[nn], acc2[m][nn], 0, 0, 0);
  }
  // epilogue 2: bias, store f32
#pragma unroll
  for (int nn = 0; nn < 4; ++nn) {
    int c = wc2 * 64 + nn * 16 + lr;
    float bv = b2[c];
#pragma unroll
    for (int m = 0; m < 2; ++m) {
#pragma unroll
      for (int j = 0; j < 4; ++j) {
        int r = mrow0 + wr2 * 32 + m * 16 + (lane >> 4) * 4 + j;
        if (r < M) out[(size_t)r * OUT_F + c] = acc2[m][nn][j] + bv;
      }
    }
  }
}

// ---------------- launch ----------------

extern "C" void kernel_launch(void* const* d_in, const int* in_sizes, int n_in,
                              void* d_out, int out_size, void* d_ws, size_t ws_size,
                              hipStream_t stream) {
  const float* x         = (const float*)d_in[0];
  const int*   edge_idx  = (const int*)d_in[1];      // [2 x N_EDGES], int32
  const int*   col       = edge_idx + N_EDGES;       // row 1 = destinations
  const float* edge_attr = (const float*)d_in[2];
  const float* W1        = (const float*)d_in[3];
  const float* b1        = (const float*)d_in[4];
  const float* W2        = (const float*)d_in[5];
  const float* b2        = (const float*)d_in[6];
  float* out = (float*)d_out;

  // workspace layout (bytes), all 16B-aligned
  char* ws = (char*)d_ws;
  unsigned* counts   = (unsigned*)(ws + 0);              // 400,000
  unsigned* total    = (unsigned*)(ws + 400000);         // 4 (+12 pad)
  unsigned* offsets  = (unsigned*)(ws + 400016);         // 400,000
  unsigned* cursor   = (unsigned*)(ws + 800016);         // 400,000
  unsigned* edge_ids = (unsigned*)(ws + 1200016);        // 6,400,000
  short*    hin      = (short*)   (ws + 7600016);        // 51,200,000 (bf16)
  short*    w1b      = (short*)   (ws + 58800016);       // 131,072
  short*    w2b      = (short*)   (ws + 58931088);       // 65,536
  // total ~59.0 MB

  hipMemsetAsync(ws, 0, 400004, stream);  // counts + total

  k_cvt2   <<<(HIDDEN * K_DIM + OUT_F * HIDDEN) / 4 / 256, 256, 0, stream>>>(W1, W2, w1b, w2b);
  k_count  <<<(N_EDGES + 255) / 256, 256, 0, stream>>>(col, counts);
  k_offsets<<<(N_NODES + 255) / 256, 256, 0, stream>>>(counts, offsets, cursor, total);
  k_fill   <<<(N_EDGES + 255) / 256, 256, 0, stream>>>(col, cursor, edge_ids);
  k_agg    <<<N_NODES / 4, 256, 0, stream>>>(x, edge_attr, offsets, counts, edge_ids, hin);
  k_mlp    <<<(N_NODES + 127) / 128, 512, 0, stream>>>(hin, w1b, b1, w2b, b2, out, N_NODES);
}